// Round 6
// baseline (217.552 us; speedup 1.0000x reference)
//
#include <hip/hip_runtime.h>

// MinVarianceWeightsLayer: for each of B SPD 64x64 fp32 matrices S,
// solve S z = 1, output w = z / sum(z) as [B, 64, 1] fp32.
//
// ROUND-6 RESTRUCTURE: rounds 1-5 pinned at VGPR_Count=68 / 26% occupancy /
// ~78us regardless of source shape -- allocator keeps the 64-float row array
// in AGPRs (unified file) and pays copies around every FMA. Fix by design:
// TWO waves per matrix, wave parity h owns interleaved columns (j&1==h) ->
// 32 floats/lane of state. Gauss-Jordan (eliminate all rows i!=k) removes
// back-substitution, so the only cross-wave traffic is the per-step nf vector
// (256 B LDS + one barrier). RHS b replicated in both waves stays identical.

#define NN 64

typedef float v2f __attribute__((ext_vector_type(2)));

template <int I> struct ic { static constexpr int value = I; };

template <int Start, int End, typename F>
__device__ __forceinline__ void static_for(F&& f) {
    if constexpr (Start < End) {
        f(ic<Start>{});
        static_for<Start + 1, End>(static_cast<F&&>(f));
    }
}

__device__ __forceinline__ float rlane(float v, int lane) {
    return __int_as_float(__builtin_amdgcn_readlane(__float_as_int(v), lane));
}

__device__ __forceinline__ float frcp(float x) {
#if __has_builtin(__builtin_amdgcn_rcpf)
    return __builtin_amdgcn_rcpf(x);
#else
    return 1.0f / x;
#endif
}

__device__ __forceinline__ v2f fma2(v2f a, v2f b, v2f c) {
#if __has_builtin(__builtin_elementwise_fma)
    return __builtin_elementwise_fma(a, b, c);   // -> v_pk_fma_f32
#else
    v2f r; r.x = fmaf(a.x, b.x, c.x); r.y = fmaf(a.y, b.y, c.y); return r;
#endif
}

__global__ __launch_bounds__(256)
__attribute__((amdgpu_waves_per_eu(6, 8)))
void minvar_kernel(const float* __restrict__ sigma,
                   float* __restrict__ out,
                   int batch) {
    __shared__ float nf_buf[2][NN];    // per-matrix nf share (single buffer is
                                       // safe: writer of step k+1 writes after
                                       // barrier k; reader consumed before it)
    __shared__ float dg_buf[2][NN];    // per-matrix diagonal share

    const int lane = threadIdx.x & 63;
    const int wid  = threadIdx.x >> 6;
    const int mloc = wid >> 1;          // matrix within block (0 or 1)
    const int h    = wid & 1;           // column parity this wave owns
    int bid = blockIdx.x * 2 + mloc;
    if (bid >= batch) bid = batch - 1;  // redundant-but-identical work; no
                                        // early exit (keeps barriers full)

    const float* __restrict__ rowp =
        sigma + (size_t)bid * (NN * NN) + (size_t)lane * NN + h;

    // r[m] = A[lane][2m+h] : this wave's 32 columns of its lane's row
    float r[NN / 2];
    static_for<0, NN / 2>([&](auto mc) {
        constexpr int m = decltype(mc)::value;
        r[m] = rowp[2 * m];
    });

    float b = 1.0f;     // RHS (ones), replicated in both waves
    float d = 0.0f;     // my diagonal (valid on lanes with lane&1 == h)
    float* __restrict__ nfp = &nf_buf[mloc][0];
    float* __restrict__ dgp = &dg_buf[mloc][0];

    static_for<0, NN>([&](auto kc) {
        constexpr int k  = decltype(kc)::value;
        constexpr int kp = k & 1;       // owner parity of column k
        constexpr int m0 = k >> 1;      // owner's register slot of column k

        float nf;
        if (h == kp) {                  // wave-uniform branch
            const float aik   = r[m0];
            const float pivot = rlane(aik, k);      // a_kk final -> d_k
            d  = (lane == k) ? pivot : d;           // lane k keeps its diag
            nf = (lane != k) ? (-aik * frcp(pivot)) : 0.0f;
            nfp[lane] = nf;
        }
        __syncthreads();
        if (h != kp) nf = nfp[lane];

        // RHS update (row k untouched since nf_k == 0)
        b = fmaf(nf, rlane(b, k), b);

        // k even: non-owner's slot m0 is column k+1 (>k) -> gated update;
        // owner's slot m0 is column k itself -> gate 0 preserves it.
        if constexpr (kp == 0) {
            const float g = (h != 0) ? nf : 0.0f;
            r[m0] = fmaf(g, rlane(r[m0], k), r[m0]);
        }

        // slots m >= m0+1 have column 2m+h > k for both parities
        constexpr int F   = m0 + 1;
        constexpr int cnt = (NN / 2) - F;
        constexpr int F2  = F + (cnt & 1);
        if constexpr (cnt & 1)
            r[F] = fmaf(nf, rlane(r[F], k), r[F]);

        const v2f nf2 = v2f{nf, nf};
        static_for<0, (NN / 2 - F2 + 7) / 8>([&](auto gc) {   // 4 pairs/group
            constexpr int g0 = F2 + 8 * decltype(gc)::value;
            v2f bc[4];
            static_for<0, 4>([&](auto tc) {     // batch readlanes first
                constexpr int t = decltype(tc)::value;
                if constexpr (g0 + 2 * t + 1 < NN / 2)
                    bc[t] = v2f{rlane(r[g0 + 2 * t], k),
                                rlane(r[g0 + 2 * t + 1], k)};
            });
            static_for<0, 4>([&](auto tc) {     // then the pk_fmas
                constexpr int t = decltype(tc)::value;
                if constexpr (g0 + 2 * t + 1 < NN / 2) {
                    v2f cur = v2f{r[g0 + 2 * t], r[g0 + 2 * t + 1]};
                    cur = fma2(nf2, bc[t], cur);
                    r[g0 + 2 * t]     = cur.x;
                    r[g0 + 2 * t + 1] = cur.y;
                }
            });
        });
    });

    // exchange diagonals: lanes matching my parity have d valid
    if ((lane & 1) == h) dgp[lane] = d;
    __syncthreads();
    const float z = b * frcp(dgp[lane]);

    // normalize: w = z / sum(z)
    float tot = z;
    #pragma unroll
    for (int off = 32; off >= 1; off >>= 1)
        tot += __shfl_xor(tot, off, 64);

    if (h == 0)
        out[(size_t)bid * NN + lane] = z * frcp(tot);
}

extern "C" void kernel_launch(void* const* d_in, const int* in_sizes, int n_in,
                              void* d_out, int out_size, void* d_ws, size_t ws_size,
                              hipStream_t stream) {
    const float* sigma = (const float*)d_in[0];
    float* out = (float*)d_out;
    const int batch  = in_sizes[0] / (NN * NN);   // 8192
    const int blocks = (batch + 1) / 2;           // 2 matrices per 256-thr block
    minvar_kernel<<<blocks, 256, 0, stream>>>(sigma, out, batch);
}

// Round 7
// 203.140 us; speedup vs baseline: 1.0709x; 1.0709x over previous
//
#include <hip/hip_runtime.h>

// MinVarianceWeightsLayer: for each of B SPD 64x64 fp32 matrices S,
// solve S z = 1, output w = z / sum(z) as [B, 64, 1] fp32.
//
// ROUND-7 RESTRUCTURE (readlane elimination). Evidence from r1-r6: total
// VALU-busy cycles are invariant (~122K/SIMD) across occupancy 2x and
// per-wave-work 0.5x changes -- the kernel is bound by v_readlane issue
// (~8 cyc each: 64-lane -> scalar port funnel). Fix: symmetric Gaussian
// elimination keeps the trailing submatrix symmetric, so pivot ROW k ==
// COLUMN k == each lane's own r[k]. Broadcast = one parallel ds_write_b32
// (lane i writes r[k]) + wave-uniform ds_read_b128 (HW broadcast, LDS pipe,
// zero VALU). One wave per matrix -> no barriers, only lgkmcnt.
// Chunk updates are unconditional: elements j<=k they touch are dead
// subdiagonal L-entries on updating lanes (i>k) -- never read afterwards.
// Diagonal & U rows stay exact (nf==0 on lanes <=k).

#define NN 64

typedef float v2f __attribute__((ext_vector_type(2)));
typedef float v4f __attribute__((ext_vector_type(4)));

template <int I> struct ic { static constexpr int value = I; };

template <int Start, int End, typename F>
__device__ __forceinline__ void static_for(F&& f) {
    if constexpr (Start < End) {
        f(ic<Start>{});
        static_for<Start + 1, End>(static_cast<F&&>(f));
    }
}

__device__ __forceinline__ float rlane(float v, int lane) {
    return __int_as_float(__builtin_amdgcn_readlane(__float_as_int(v), lane));
}

__device__ __forceinline__ float frcp(float x) {
#if __has_builtin(__builtin_amdgcn_rcpf)
    return __builtin_amdgcn_rcpf(x);   // ~1 ulp; plenty vs 2e-3 abs threshold
#else
    return 1.0f / x;
#endif
}

__device__ __forceinline__ v2f fma2(v2f a, v2f b, v2f c) {
#if __has_builtin(__builtin_elementwise_fma)
    return __builtin_elementwise_fma(a, b, c);   // -> v_pk_fma_f32
#else
    v2f r; r.x = fmaf(a.x, b.x, c.x); r.y = fmaf(a.y, b.y, c.y); return r;
#endif
}

__global__ __launch_bounds__(256) void minvar_kernel(const float* __restrict__ sigma,
                                                     float* __restrict__ out,
                                                     int batch) {
    __shared__ v4f buf[4][16];           // per-wave 64-float broadcast buffer

    const int lane = threadIdx.x & 63;
    const int wid  = threadIdx.x >> 6;   // 4 waves/block, 1 matrix each
    const int bid  = blockIdx.x * 4 + wid;
    if (bid >= batch) return;            // no barriers anywhere -> safe

    const float* __restrict__ p = sigma + (size_t)bid * (NN * NN) + (size_t)lane * NN;

    // lane i's row as 32 even-aligned float2 pairs
    v2f r[NN / 2];
    static_for<0, NN / 4>([&](auto j4c) {
        constexpr int j4 = decltype(j4c)::value;
        v4f v = reinterpret_cast<const v4f*>(p)[j4];
        r[2 * j4 + 0] = v2f{v.x, v.y};
        r[2 * j4 + 1] = v2f{v.z, v.w};
    });

    float b = 1.0f;                      // RHS: ones
    float* __restrict__ fbuf = reinterpret_cast<float*>(&buf[wid][0]);

    // ---- Forward elimination (symmetric: row k broadcast == column k) ----
    static_for<0, NN>([&](auto kc) {
        constexpr int k  = decltype(kc)::value;
        constexpr int c0 = k >> 2;       // chunk holding the pivot
        constexpr int e0 = k & 3;

        const float colk = (k & 1) ? r[k / 2].y : r[k / 2].x;  // A[lane][k]
        fbuf[lane] = colk;                           // publish column k
        __asm__ volatile("s_waitcnt lgkmcnt(0)" ::: "memory");

        const v4f q0 = buf[wid][c0];                 // uniform b128 broadcast
        const float pivot = q0[e0];                  // A[k][k] (uniform)
        const float nf = (lane > k) ? (-colk * frcp(pivot)) : 0.0f;
        b = fmaf(nf, rlane(b, k), b);                // RHS (1 readlane/step)
        const v2f nf2 = v2f{nf, nf};

        // pivot chunk: j<k parts are dead subdiagonal on updating lanes
        r[2 * c0 + 0] = fma2(nf2, v2f{q0.x, q0.y}, r[2 * c0 + 0]);
        r[2 * c0 + 1] = fma2(nf2, v2f{q0.z, q0.w}, r[2 * c0 + 1]);

        // remaining chunks, fixed groups of 4 (bounds VGPR pressure)
        static_for<0, 4>([&](auto gc) {
            constexpr int g = decltype(gc)::value;
            if constexpr (4 * g + 3 > c0) {
                v4f q[4];
                static_for<0, 4>([&](auto tc) {      // batch the reads
                    constexpr int t = decltype(tc)::value;
                    if constexpr (4 * g + t > c0) q[t] = buf[wid][4 * g + t];
                });
                static_for<0, 4>([&](auto tc) {      // then the pk_fmas
                    constexpr int t = decltype(tc)::value;
                    constexpr int c = 4 * g + t;
                    if constexpr (c > c0) {
                        r[2 * c + 0] = fma2(nf2, v2f{q[t].x, q[t].y}, r[2 * c + 0]);
                        r[2 * c + 1] = fma2(nf2, v2f{q[t].z, q[t].w}, r[2 * c + 1]);
                    }
                });
            }
        });
    });

    // ---- Back substitution (diag & U intact; 2 readlanes/step) ----
    static_for<0, NN>([&](auto kk) {
        constexpr int k  = NN - 1 - decltype(kk)::value;
        constexpr int pk = k / 2;
        const float ekk  = (k & 1) ? r[pk].y : r[pk].x;
        const float ukk  = rlane(ekk, k);
        const float yk   = rlane(b, k);
        const float zk   = yk * frcp(ukk);
        const float upd  = (lane < k) ? (-ekk) : 0.0f;
        b = (lane == k) ? zk : fmaf(upd, zk, b);
    });

    // ---- Normalize: w = z / sum(z) ----
    float tot = b;
    #pragma unroll
    for (int off = 32; off >= 1; off >>= 1)
        tot += __shfl_xor(tot, off, 64);

    out[(size_t)bid * NN + lane] = b * frcp(tot);
}

extern "C" void kernel_launch(void* const* d_in, const int* in_sizes, int n_in,
                              void* d_out, int out_size, void* d_ws, size_t ws_size,
                              hipStream_t stream) {
    const float* sigma = (const float*)d_in[0];
    float* out = (float*)d_out;
    const int batch  = in_sizes[0] / (NN * NN);   // 8192
    const int blocks = (batch + 3) / 4;           // 4 matrices per 256-thr block
    minvar_kernel<<<blocks, 256, 0, stream>>>(sigma, out, batch);
}

// Round 8
// 201.426 us; speedup vs baseline: 1.0801x; 1.0085x over previous
//
#include <hip/hip_runtime.h>

// MinVarianceWeightsLayer: for each of B SPD 64x64 fp32 matrices S,
// solve S z = 1, output w = z / sum(z) as [B, 64, 1] fp32.
//
// ROUND-8: rank-4 panel elimination. r7 evidence: per-step LDS round trip
// fully exposed (VALUBusy 25%, 116us). Here the broadcast is amortized:
// 16 panels x (readlane-only in-panel phase -> ONE publish of 4 columns ->
// ONE rank-4 chunk pass). Symmetry: eliminated column == pivot row, so each
// lane publishes its own 4 panel elements (post in-panel update); trailing
// submatrix symmetry makes published A[j][kc] == row-kc value u_c[j].
// LDS layout pb[m][c][par] (v2f-interleaved) so each uniform ds_read_b128
// returns two ready v2f operands for v_pk_fma_f32 -- zero repacking.
// One wave per matrix, NO barriers (DS ops are in-order within a wave).

#define NN 64

typedef float v2f __attribute__((ext_vector_type(2)));
typedef float v4f __attribute__((ext_vector_type(4)));

template <int I> struct ic { static constexpr int value = I; };

template <int Start, int End, typename F>
__device__ __forceinline__ void static_for(F&& f) {
    if constexpr (Start < End) {
        f(ic<Start>{});
        static_for<Start + 1, End>(static_cast<F&&>(f));
    }
}

__device__ __forceinline__ float rlane(float v, int lane) {
    return __int_as_float(__builtin_amdgcn_readlane(__float_as_int(v), lane));
}

__device__ __forceinline__ float frcp(float x) {
#if __has_builtin(__builtin_amdgcn_rcpf)
    return __builtin_amdgcn_rcpf(x);   // ~1 ulp; plenty vs 2e-3 abs threshold
#else
    return 1.0f / x;
#endif
}

__device__ __forceinline__ v2f fma2(v2f a, v2f b, v2f c) {
#if __has_builtin(__builtin_elementwise_fma)
    return __builtin_elementwise_fma(a, b, c);   // -> v_pk_fma_f32
#else
    v2f r; r.x = fmaf(a.x, b.x, c.x); r.y = fmaf(a.y, b.y, c.y); return r;
#endif
}

__global__ __launch_bounds__(256) void minvar_kernel(const float* __restrict__ sigma,
                                                     float* __restrict__ out,
                                                     int batch) {
    // [wave][panel parity][ m*8 + c*2 + par ] : u_c[2m+par]
    __shared__ float pb[4][2][2 * NN * 4 / 2];   // 4 waves x 2 x 256 floats = 8 KB

    const int lane = threadIdx.x & 63;
    const int wid  = threadIdx.x >> 6;     // 4 waves/block, 1 matrix each
    const int bid  = blockIdx.x * 4 + wid;
    if (bid >= batch) return;              // no barriers anywhere -> safe

    const float* __restrict__ p = sigma + (size_t)bid * (NN * NN) + (size_t)lane * NN;

    // lane i's row as 32 float2 pairs (all indices compile-time -> VGPRs)
    v2f r[NN / 2];
    static_for<0, NN / 4>([&](auto j4c) {
        constexpr int j4 = decltype(j4c)::value;
        v4f v = reinterpret_cast<const v4f*>(p)[j4];
        r[2 * j4 + 0] = v2f{v.x, v.y};
        r[2 * j4 + 1] = v2f{v.z, v.w};
    });

    float b = 1.0f;                        // RHS: ones
    const int wbase = (lane >> 1) * 8 + (lane & 1);   // scatter-write index

    static_for<0, 16>([&](auto pc) {
        constexpr int P  = decltype(pc)::value;
        constexpr int k0 = 4 * P;
        constexpr int m0 = 2 * P;          // pair-slots m0, m0+1 are the panel
        float* __restrict__ wb = &pb[wid][P & 1][0];

        // ---- phase 1: in-panel elimination (readlane only, all local) ----
        const float el0  = r[m0].x;                    // A[i][k0] (pre-panel)
        const float piv0 = rlane(el0, k0);
        const float nf0  = (lane > k0) ? (-el0 * frcp(piv0)) : 0.0f;
        b = fmaf(nf0, rlane(b, k0), b);
        const float u01 = rlane(r[m0].y,     k0);
        const float u02 = rlane(r[m0 + 1].x, k0);
        const float u03 = rlane(r[m0 + 1].y, k0);
        r[m0].y     = fmaf(nf0, u01, r[m0].y);
        r[m0 + 1].x = fmaf(nf0, u02, r[m0 + 1].x);
        r[m0 + 1].y = fmaf(nf0, u03, r[m0 + 1].y);

        const float el1  = r[m0].y;                    // A[i][k0+1] after c0
        const float piv1 = rlane(el1, k0 + 1);
        const float nf1  = (lane > k0 + 1) ? (-el1 * frcp(piv1)) : 0.0f;
        b = fmaf(nf1, rlane(b, k0 + 1), b);
        const float u12 = rlane(r[m0 + 1].x, k0 + 1);
        const float u13 = rlane(r[m0 + 1].y, k0 + 1);
        r[m0 + 1].x = fmaf(nf1, u12, r[m0 + 1].x);
        r[m0 + 1].y = fmaf(nf1, u13, r[m0 + 1].y);

        const float el2  = r[m0 + 1].x;                // A[i][k0+2] after c0,c1
        const float piv2 = rlane(el2, k0 + 2);
        const float nf2  = (lane > k0 + 2) ? (-el2 * frcp(piv2)) : 0.0f;
        b = fmaf(nf2, rlane(b, k0 + 2), b);
        const float u23 = rlane(r[m0 + 1].y, k0 + 2);
        r[m0 + 1].y = fmaf(nf2, u23, r[m0 + 1].y);

        const float el3  = r[m0 + 1].y;                // A[i][k0+3] after c0..c2
        const float piv3 = rlane(el3, k0 + 3);
        const float nf3  = (lane > k0 + 3) ? (-el3 * frcp(piv3)) : 0.0f;
        b = fmaf(nf3, rlane(b, k0 + 3), b);

        if constexpr (P < 15) {
            // ---- phase 2: publish the 4 eliminated columns (transposed) ----
            wb[wbase + 0] = el0;
            wb[wbase + 2] = el1;
            wb[wbase + 4] = el2;
            wb[wbase + 6] = el3;

            // ---- phase 3: rank-4 update of trailing pair-slots ----
            const v2f n0 = v2f{nf0, nf0}, n1 = v2f{nf1, nf1};
            const v2f n2 = v2f{nf2, nf2}, n3 = v2f{nf3, nf3};
            static_for<m0 + 2, NN / 2>([&](auto mc) {
                constexpr int m = decltype(mc)::value;
                const v4f lo = *reinterpret_cast<const v4f*>(wb + 8 * m);     // u0,u1 pairs
                const v4f hi = *reinterpret_cast<const v4f*>(wb + 8 * m + 4); // u2,u3 pairs
                v2f acc = r[m];
                acc = fma2(n0, v2f{lo.x, lo.y}, acc);
                acc = fma2(n1, v2f{lo.z, lo.w}, acc);
                acc = fma2(n2, v2f{hi.x, hi.y}, acc);
                acc = fma2(n3, v2f{hi.z, hi.w}, acc);
                r[m] = acc;
            });
        }
    });

    // ---- back substitution (U rows intact; gated updates above diag) ----
    static_for<0, NN>([&](auto kk) {
        constexpr int k  = NN - 1 - decltype(kk)::value;
        constexpr int pk = k / 2;
        const float ekk = (k & 1) ? r[pk].y : r[pk].x;
        const float ukk = rlane(ekk, k);
        const float yk  = rlane(b, k);
        const float zk  = yk * frcp(ukk);
        const float upd = (lane < k) ? (-ekk) : 0.0f;
        b = (lane == k) ? zk : fmaf(upd, zk, b);
    });

    // ---- normalize: w = z / sum(z) ----
    float tot = b;
    #pragma unroll
    for (int off = 32; off >= 1; off >>= 1)
        tot += __shfl_xor(tot, off, 64);

    out[(size_t)bid * NN + lane] = b * frcp(tot);
}

extern "C" void kernel_launch(void* const* d_in, const int* in_sizes, int n_in,
                              void* d_out, int out_size, void* d_ws, size_t ws_size,
                              hipStream_t stream) {
    const float* sigma = (const float*)d_in[0];
    float* out = (float*)d_out;
    const int batch  = in_sizes[0] / (NN * NN);   // 8192
    const int blocks = (batch + 3) / 4;           // 4 matrices per 256-thr block
    minvar_kernel<<<blocks, 256, 0, stream>>>(sigma, out, batch);
}